// Round 4
// baseline (145.431 us; speedup 1.0000x reference)
//
#include <hip/hip_runtime.h>

// Involution: B=4, C=256, H=W=56, K=7, GC=16 -> G=16, Cr=64, K2=49
// SINGLE fused kernel, grid (49,16,4) x 256 threads:
//   phase 1: conv1 for this block's 64-px tile (all 256 in-ch, 4x64c chunks,
//            f16 MFMA, BN folded) -> mid tile kept in LDS [64px][72] f16.
//   phase 2: conv2 GEMM (f16 MFMA) -> lw2 [49][68] f32.
//   phase 3: halo x (16 ch of this group) -> lx f32, overlay on conv1 bufs.
//   phase 4: fp32 unfold/apply -> out.
// Removes: k1 dispatch + mid HBM round-trip. conv1 redone per-group (16x);
// x/w1 re-reads are L2/L3-resident. ws unused.

#define EPS 1e-5f

typedef __fp16 half2t __attribute__((ext_vector_type(2)));
typedef __fp16 half8t __attribute__((ext_vector_type(8)));
typedef float floatx4 __attribute__((ext_vector_type(4)));

__device__ inline half8t pack8(float4 u0, float4 u1, float s) {
    half8t a;
    half2t q;
    q = __builtin_amdgcn_cvt_pkrtz(u0.x * s, u0.y * s); a[0] = q[0]; a[1] = q[1];
    q = __builtin_amdgcn_cvt_pkrtz(u0.z * s, u0.w * s); a[2] = q[0]; a[3] = q[1];
    q = __builtin_amdgcn_cvt_pkrtz(u1.x * s, u1.y * s); a[4] = q[0]; a[5] = q[1];
    q = __builtin_amdgcn_cvt_pkrtz(u1.z * s, u1.w * s); a[6] = q[0]; a[7] = q[1];
    return a;
}

// LDS map (bytes):
//   [0, 9216)       bufA  [64px][72] f16  - conv1 x-chunk staging
//   [9216, 18432)   lmid  [64px][72] f16  - conv1 output tile (GEMM B-op)
//   [0, 15616)      lx    [16ch][244] f32 - halo, overlays bufA+lmid AFTER GEMM
//   [18432, 31760)  lw2   [49][68]   f32  - generated weights
__global__ __launch_bounds__(256, 4) void k_fused(
    const float* __restrict__ x, const float* __restrict__ w1,
    const float* __restrict__ gamma, const float* __restrict__ beta,
    const float* __restrict__ mean, const float* __restrict__ var,
    const float* __restrict__ cw, const float* __restrict__ cb,
    float* __restrict__ out)
{
    __shared__ __align__(16) unsigned char smem[31760];
    __fp16* bufA = (__fp16*)smem;
    __fp16* lmid = (__fp16*)(smem + 9216);
    float*  lx   = (float*)smem;
    float*  lw2  = (float*)(smem + 18432);

    const int t  = threadIdx.x;
    const int b  = blockIdx.z;
    const int g  = blockIdx.y;
    const int th = blockIdx.x / 7, tw = blockIdx.x % 7;
    const int h0 = th * 8, w0 = tw * 8;
    const int lane = t & 63, wvid = t >> 6;
    const int mrow = lane & 15, quad = lane >> 4;

    // ---------------- phase 1: conv1 on this tile (64px x 64o, K=256) ------
    const int orow = wvid * 16 + mrow;
    const float s1 = gamma[orow] * rsqrtf(var[orow] + EPS);

    const int c2 = t & 31, px8 = t >> 5;       // ch-pair in chunk, px-row 0..7
    floatx4 acc1[4] = {};
#pragma unroll
    for (int ch = 0; ch < 4; ++ch) {
        // x chunk: rows c = 2*c2, 2*c2+1 of this 64-ch chunk, 8 px (one tile row)
        const float* r0 = &x[(size_t)(b * 256 + ch * 64 + 2 * c2) * 3136 +
                             (h0 + px8) * 56 + w0];
        float4 xa0 = *(const float4*)r0;
        float4 xa1 = *(const float4*)(r0 + 4);
        float4 xb0 = *(const float4*)(r0 + 3136);
        float4 xb1 = *(const float4*)(r0 + 3140);
        // A-frags for this chunk (w1 L2-hot), BN scale folded
        const float* wsrc = &w1[orow * 256 + ch * 64 + quad * 8];
        half8t A0 = pack8(*(const float4*)wsrc,        *(const float4*)(wsrc + 4),  s1);
        half8t A1 = pack8(*(const float4*)(wsrc + 32), *(const float4*)(wsrc + 36), s1);

        float fa[8], fb[8];
        fa[0]=xa0.x; fa[1]=xa0.y; fa[2]=xa0.z; fa[3]=xa0.w;
        fa[4]=xa1.x; fa[5]=xa1.y; fa[6]=xa1.z; fa[7]=xa1.w;
        fb[0]=xb0.x; fb[1]=xb0.y; fb[2]=xb0.z; fb[3]=xb0.w;
        fb[4]=xb1.x; fb[5]=xb1.y; fb[6]=xb1.z; fb[7]=xb1.w;
#pragma unroll
        for (int j = 0; j < 8; ++j) {
            half2t q = __builtin_amdgcn_cvt_pkrtz(fa[j], fb[j]);
            *(half2t*)&bufA[(px8 * 8 + j) * 72 + 2 * c2] = q;
        }
        __syncthreads();
#pragma unroll
        for (int pt = 0; pt < 4; ++pt) {
            half8t bf0 = *(const half8t*)&bufA[(pt * 16 + mrow) * 72 + quad * 8];
            half8t bf1 = *(const half8t*)&bufA[(pt * 16 + mrow) * 72 + quad * 8 + 32];
            acc1[pt] = __builtin_amdgcn_mfma_f32_16x16x32_f16(A0, bf0, acc1[pt], 0, 0, 0);
            acc1[pt] = __builtin_amdgcn_mfma_f32_16x16x32_f16(A1, bf1, acc1[pt], 0, 0, 0);
        }
        __syncthreads();
    }

    // ---- halo loads: issue now, consumed in phase 3 (latency hides under
    //      conv1 epilogue + GEMM) ----
    float4 rv4[4];
#pragma unroll
    for (int i = 0; i < 4; ++i) {
        int s = t + i * 256;
        float4 v = make_float4(0.f, 0.f, 0.f, 0.f);
        if (s < 896) {
            int chh = s / 56, r = s % 56;
            int row = r >> 2, q = r & 3;
            int gh = h0 + row - 3;
            int gwb = w0 - 4 + q * 4;
            bool ok = (gh >= 0) & (gh < 56) & (gwb >= 0) & (gwb <= 52);
            int ghc = min(max(gh, 0), 55);
            int gwc = min(max(gwb, 0), 52);
            float4 ld = *(const float4*)&x[(size_t)(b * 256 + g * 16 + chh) * 3136 +
                                           ghc * 56 + gwc];
            if (ok) v = ld;
        }
        rv4[i] = v;
    }

    // ---- conv2 A-frags (cw L2-hot): issue before conv1 epilogue ----
    const int krow = wvid * 16 + mrow;
    half8t a0 = {}, a1 = {};
    if (krow < 49) {
        const float* src = &cw[(size_t)(g * 49 + krow) * 64 + quad * 8];
        a0 = pack8(*(const float4*)src,        *(const float4*)(src + 4),  1.f);
        a1 = pack8(*(const float4*)(src + 32), *(const float4*)(src + 36), 1.f);
    }

    // ---- conv1 epilogue: bias + relu -> lmid [px][c] f16 (stride 72) ----
    {
        float bb[4];
#pragma unroll
        for (int i = 0; i < 4; ++i) {
            int o = wvid * 16 + quad * 4 + i;
            float so = gamma[o] * rsqrtf(var[o] + EPS);
            bb[i] = beta[o] - mean[o] * so;
        }
#pragma unroll
        for (int pt = 0; pt < 4; ++pt)
#pragma unroll
            for (int i = 0; i < 4; ++i) {
                float v = fmaxf(acc1[pt][i] + bb[i], 0.f);
                lmid[(pt * 16 + mrow) * 72 + wvid * 16 + quad * 4 + i] = (__fp16)v;
            }
    }
    __syncthreads();

    // ---------------- phase 2: conv2 GEMM D[49 ko x 64 px] -----------------
    {
        float bias[4];
        int   kor[4];
#pragma unroll
        for (int i = 0; i < 4; ++i) {
            kor[i]  = wvid * 16 + quad * 4 + i;
            bias[i] = (kor[i] < 49) ? cb[g * 49 + kor[i]] : 0.f;
        }
#pragma unroll
        for (int pt = 0; pt < 4; ++pt) {
            half8t b0 = *(const half8t*)&lmid[(pt * 16 + mrow) * 72 + quad * 8];
            half8t b1 = *(const half8t*)&lmid[(pt * 16 + mrow) * 72 + quad * 8 + 32];
            floatx4 acc = {0.f, 0.f, 0.f, 0.f};
            acc = __builtin_amdgcn_mfma_f32_16x16x32_f16(a0, b0, acc, 0, 0, 0);
            acc = __builtin_amdgcn_mfma_f32_16x16x32_f16(a1, b1, acc, 0, 0, 0);
#pragma unroll
            for (int i = 0; i < 4; ++i)
                if (kor[i] < 49)
                    lw2[kor[i] * 68 + pt * 16 + mrow] = acc[i] + bias[i];
        }
    }
    __syncthreads();

    // ---------------- phase 3: halo regs -> lx (overlay, conv1 bufs dead) --
#pragma unroll
    for (int i = 0; i < 4; ++i) {
        int s = t + i * 256;
        if (s < 896) {
            int chh = s / 56, r = s % 56;
            int row = r >> 2, q = r & 3;
            float* dst = &lx[chh * 244 + row * 17 + q * 4];
            dst[0] = rv4[i].x; dst[1] = rv4[i].y;
            dst[2] = rv4[i].z; dst[3] = rv4[i].w;
        }
    }
    __syncthreads();

    // ---------------- phase 4: fp32 unfold/apply ---------------------------
    const int cc = t >> 4, pxt = t & 15;
    const int sh = pxt >> 1, sw4 = (pxt & 1) * 4;
    float a0f = 0.f, a1f = 0.f, a2f = 0.f, a3f = 0.f;
#pragma unroll
    for (int kh = 0; kh < 7; ++kh) {
        float xr[10];
        const int base = cc * 244 + (sh + kh) * 17 + sw4 + 1;
#pragma unroll
        for (int j = 0; j < 10; ++j) xr[j] = lx[base + j];
#pragma unroll
        for (int kw = 0; kw < 7; ++kw) {
            const float4 wv = *(const float4*)&lw2[(kh * 7 + kw) * 68 + pxt * 4];
            a0f = fmaf(wv.x, xr[kw + 0], a0f);
            a1f = fmaf(wv.y, xr[kw + 1], a1f);
            a2f = fmaf(wv.z, xr[kw + 2], a2f);
            a3f = fmaf(wv.w, xr[kw + 3], a3f);
        }
    }
    *(float4*)&out[(b * 256 + g * 16 + cc) * 3136 + (h0 + sh) * 56 + w0 + sw4] =
        make_float4(a0f, a1f, a2f, a3f);
}

extern "C" void kernel_launch(void* const* d_in, const int* in_sizes, int n_in,
                              void* d_out, int out_size, void* d_ws, size_t ws_size,
                              hipStream_t stream) {
    const float* x     = (const float*)d_in[0];
    const float* w1    = (const float*)d_in[1];
    const float* gamma = (const float*)d_in[2];
    const float* beta  = (const float*)d_in[3];
    const float* mean  = (const float*)d_in[4];
    const float* var   = (const float*)d_in[5];
    const float* cw    = (const float*)d_in[6];
    const float* cb    = (const float*)d_in[7];
    float* out = (float*)d_out;

    (void)d_ws; (void)ws_size;

    k_fused<<<dim3(49, 16, 4), 256, 0, stream>>>(x, w1, gamma, beta, mean, var,
                                                 cw, cb, out);
}

// Round 5
// 112.020 us; speedup vs baseline: 1.2983x; 1.2983x over previous
//
#include <hip/hip_runtime.h>

// Involution: B=4, C=256, H=W=56, K=7, GC=16 -> G=16, Cr=64, K2=49
// R5: two-kernel (R3 structure, best measured: ~43us device work) with
//  - k1: coalesced staging (px-quad in low lane bits -> 64B bursts; half2
//        LDS writes stay 2-way-free), loads still hoisted.
//  - k2: apply x-reads as 3x float4 per kh (lx row stride 20 dwords, even
//        bank-group spread), float4 halo LDS stores. Structure unchanged.
// ws: mid f16 [4][3136 px][64 c] @0 (1605632 B).

#define EPS 1e-5f

typedef __fp16 half2t __attribute__((ext_vector_type(2)));
typedef __fp16 half8t __attribute__((ext_vector_type(8)));
typedef float floatx4 __attribute__((ext_vector_type(4)));

__device__ inline half8t pack8(float4 u0, float4 u1, float s) {
    half8t a;
    half2t q;
    q = __builtin_amdgcn_cvt_pkrtz(u0.x * s, u0.y * s); a[0] = q[0]; a[1] = q[1];
    q = __builtin_amdgcn_cvt_pkrtz(u0.z * s, u0.w * s); a[2] = q[0]; a[3] = q[1];
    q = __builtin_amdgcn_cvt_pkrtz(u1.x * s, u1.y * s); a[4] = q[0]; a[5] = q[1];
    q = __builtin_amdgcn_cvt_pkrtz(u1.z * s, u1.w * s); a[6] = q[0]; a[7] = q[1];
    return a;
}

// ---------------- Kernel 1: conv1 (1x1, 256->64) + BN + ReLU, MFMA ----------
// grid (98,4): block 64o x 32px. Staging: thread = (ch-pair p, px-quad pxq),
// pxq in low lane bits -> 4-lane 64B contiguous global bursts; half2 LDS
// writes (ch-pairs) conflict-free. All 4 chunks' loads hoisted.
__global__ __launch_bounds__(256, 4) void k1_conv1(
    const float* __restrict__ x, const float* __restrict__ w1,
    const float* __restrict__ gamma, const float* __restrict__ beta,
    const float* __restrict__ mean, const float* __restrict__ var,
    __fp16* __restrict__ mid)
{
    __shared__ __align__(16) __fp16 lxB[4 * 32 * 72];  // [chunk][px][72]
    const int t    = threadIdx.x;
    const int b    = blockIdx.y;
    const int p0   = blockIdx.x * 32;
    const int lane = t & 63, wvid = t >> 6;
    const int mrow = lane & 15, quad = lane >> 4;

    // staging map: pair p in 0..31, px-quad pxq in 0..7
    const int p   = (lane >> 2) + 16 * (wvid & 1);
    const int pxq = (lane & 3) + 4 * (wvid >> 1);

    // ---- all 4 chunks' loads in flight ----
    float4 ra[4], rb[4];
#pragma unroll
    for (int ch = 0; ch < 4; ++ch) {
        const float* r0 = &x[(size_t)(b * 256 + ch * 64 + 2 * p) * 3136 + p0 + pxq * 4];
        ra[ch] = *(const float4*)r0;
        rb[ch] = *(const float4*)(r0 + 3136);
    }

    // ---- A-fragments meanwhile: BN scale folded, f32 -> f16 (w1 L2-hot) ----
    const int orow = wvid * 16 + mrow;
    const float s = gamma[orow] * rsqrtf(var[orow] + EPS);
    half8t A[4][2];
#pragma unroll
    for (int ch = 0; ch < 4; ++ch)
#pragma unroll
        for (int h = 0; h < 2; ++h) {
            const float* src = &w1[orow * 256 + ch * 64 + h * 32 + quad * 8];
            A[ch][h] = pack8(*(const float4*)src, *(const float4*)(src + 4), s);
        }

    // ---- write all chunks to LDS (half2 ch-pairs), one barrier ----
#pragma unroll
    for (int ch = 0; ch < 4; ++ch) {
        const float* f0 = (const float*)&ra[ch];
        const float* f1 = (const float*)&rb[ch];
#pragma unroll
        for (int j = 0; j < 4; ++j) {
            half2t q = __builtin_amdgcn_cvt_pkrtz(f0[j], f1[j]);
            *(half2t*)&lxB[ch * 2304 + (pxq * 4 + j) * 72 + 2 * p] = q;
        }
    }
    __syncthreads();

    // ---- MFMA: 16 per wave, no intervening barriers ----
    floatx4 acc[2] = {};
#pragma unroll
    for (int ch = 0; ch < 4; ++ch)
#pragma unroll
        for (int pt = 0; pt < 2; ++pt) {
            half8t bf0 = *(const half8t*)&lxB[ch * 2304 + (pt * 16 + mrow) * 72 + quad * 8];
            half8t bf1 = *(const half8t*)&lxB[ch * 2304 + (pt * 16 + mrow) * 72 + quad * 8 + 32];
            acc[pt] = __builtin_amdgcn_mfma_f32_16x16x32_f16(A[ch][0], bf0, acc[pt], 0, 0, 0);
            acc[pt] = __builtin_amdgcn_mfma_f32_16x16x32_f16(A[ch][1], bf1, acc[pt], 0, 0, 0);
        }
    __syncthreads();

    // ---- epilogue: bias + relu -> f16, transpose via lxB, b128 out ----
    float bb[4];
#pragma unroll
    for (int i = 0; i < 4; ++i) {
        int o = wvid * 16 + quad * 4 + i;
        float so = gamma[o] * rsqrtf(var[o] + EPS);
        bb[i] = beta[o] - mean[o] * so;
    }
#pragma unroll
    for (int pt = 0; pt < 2; ++pt)
#pragma unroll
        for (int i = 0; i < 4; ++i) {
            float v = fmaxf(acc[pt][i] + bb[i], 0.f);
            lxB[(pt * 16 + mrow) * 72 + wvid * 16 + quad * 4 + i] = (__fp16)v;
        }
    __syncthreads();
    {
        int px = t >> 3, o8 = t & 7;                 // 256 slots = 32px x 8
        *(half8t*)&mid[(size_t)(b * 3136 + p0 + px) * 64 + o8 * 8] =
            *(const half8t*)&lxB[px * 72 + o8 * 8];
    }
}

// ---------------- Kernel 2: fused conv2 (f16 MFMA) + unfold/apply (fp32) ----
// LDS map (bytes):
//   [0, 9216)      lmid [64px][72] f16      (GEMM phase only)
//   [0, 17920)     lx   [16ch][14r][20] f32 (halo, overlays lmid AFTER GEMM)
//   [17920, 31248) lw2  [49][68] f32        (generated weights)
__global__ __launch_bounds__(256, 5) void k23_fused(
    const float* __restrict__ x, const __fp16* __restrict__ mid,
    const float* __restrict__ cw, const float* __restrict__ cb,
    float* __restrict__ out)
{
    __shared__ __align__(16) unsigned char smem[31248];
    __fp16* lmid = (__fp16*)smem;
    float*  lx   = (float*)smem;                 // ch stride 280, row stride 20
    float*  lw2  = (float*)(smem + 17920);

    const int t  = threadIdx.x;
    const int b  = blockIdx.z;
    const int g  = blockIdx.y;
    const int th = blockIdx.x / 7, tw = blockIdx.x % 7;
    const int h0 = th * 8, w0 = tw * 8;
    const int lane = t & 63, wvid = t >> 6;
    const int mrow = lane & 15, quad = lane >> 4;

    // ---- halo prefetch FIRST: 16ch x 14rows x 4 f4 (cols w0-4..w0+11) ----
    float4 rv4[4];
    int    rslot[4];
#pragma unroll
    for (int i = 0; i < 4; ++i) {
        int s = t + i * 256;
        rslot[i] = s;
        float4 v = make_float4(0.f, 0.f, 0.f, 0.f);
        if (s < 896) {
            int ch = s / 56, r = s % 56;
            int row = r >> 2, q = r & 3;
            int gh = h0 + row - 3;
            int gwb = w0 - 4 + q * 4;
            bool ok = (gh >= 0) & (gh < 56) & (gwb >= 0) & (gwb <= 52);
            int ghc = min(max(gh, 0), 55);
            int gwc = min(max(gwb, 0), 52);
            float4 ld = *(const float4*)&x[(size_t)(b * 256 + g * 16 + ch) * 3136 +
                                           ghc * 56 + gwc];
            if (ok) v = ld;
        }
        rv4[i] = v;
    }

    // A-fragments: cw f32 -> f16 inline (L2-hot); rows >=49 are zero
    const int krow = wvid * 16 + mrow;
    half8t a0 = {}, a1 = {};
    if (krow < 49) {
        const float* src = &cw[(size_t)(g * 49 + krow) * 64 + quad * 8];
        a0 = pack8(*(const float4*)src,        *(const float4*)(src + 4),  1.f);
        a1 = pack8(*(const float4*)(src + 32), *(const float4*)(src + 36), 1.f);
    }

    // stage lmid [px][c] (stride 72): contiguous-slot b128 copies
#pragma unroll
    for (int i = 0; i < 2; ++i) {
        int s  = t + i * 256;
        int px = s >> 3, c8 = s & 7;
        int pix = (h0 + (px >> 3)) * 56 + w0 + (px & 7);
        *(half8t*)&lmid[px * 72 + c8 * 8] =
            *(const half8t*)&mid[(size_t)(b * 3136 + pix) * 64 + c8 * 8];
    }
    __syncthreads();

    // MFMA GEMM: D[ko][px] = sum_c W[ko][c] * M[c][px]
    {
        float bias[4];
        int   kor[4];
#pragma unroll
        for (int i = 0; i < 4; ++i) {
            kor[i]  = wvid * 16 + quad * 4 + i;
            bias[i] = (kor[i] < 49) ? cb[g * 49 + kor[i]] : 0.f;
        }
#pragma unroll
        for (int pt = 0; pt < 4; ++pt) {
            half8t b0 = *(const half8t*)&lmid[(pt * 16 + mrow) * 72 + quad * 8];
            half8t b1 = *(const half8t*)&lmid[(pt * 16 + mrow) * 72 + quad * 8 + 32];
            floatx4 acc = {0.f, 0.f, 0.f, 0.f};
            acc = __builtin_amdgcn_mfma_f32_16x16x32_f16(a0, b0, acc, 0, 0, 0);
            acc = __builtin_amdgcn_mfma_f32_16x16x32_f16(a1, b1, acc, 0, 0, 0);
#pragma unroll
            for (int i = 0; i < 4; ++i)
                if (kor[i] < 49)
                    lw2[kor[i] * 68 + pt * 16 + mrow] = acc[i] + bias[i];
        }
    }
    __syncthreads();

    // halo f4 regs -> lx (ch stride 280, row stride 20): single float4 stores
#pragma unroll
    for (int i = 0; i < 4; ++i) {
        int s = rslot[i];
        if (s < 896) {
            int ch = s / 56, r = s % 56;
            int row = r >> 2, q = r & 3;
            *(float4*)&lx[ch * 280 + row * 20 + q * 4] = rv4[i];
        }
    }
    __syncthreads();

    // apply: thread = (cc = t>>4, 4 consecutive out px); 3x float4 lx reads/kh
    const int cc = t >> 4, pxt = t & 15;
    const int sh = pxt >> 1, sw4 = (pxt & 1) * 4;
    float a0f = 0.f, a1f = 0.f, a2f = 0.f, a3f = 0.f;
#pragma unroll
    for (int kh = 0; kh < 7; ++kh) {
        const int rb = cc * 280 + (sh + kh) * 20 + sw4;
        float4 f0 = *(const float4*)&lx[rb];
        float4 f1 = *(const float4*)&lx[rb + 4];
        float4 f2 = *(const float4*)&lx[rb + 8];
        float xw[12];
        xw[0]=f0.x; xw[1]=f0.y; xw[2]=f0.z; xw[3]=f0.w;
        xw[4]=f1.x; xw[5]=f1.y; xw[6]=f1.z; xw[7]=f1.w;
        xw[8]=f2.x; xw[9]=f2.y; xw[10]=f2.z; xw[11]=f2.w;
#pragma unroll
        for (int kw = 0; kw < 7; ++kw) {
            const float4 wv = *(const float4*)&lw2[(kh * 7 + kw) * 68 + pxt * 4];
            a0f = fmaf(wv.x, xw[kw + 1], a0f);
            a1f = fmaf(wv.y, xw[kw + 2], a1f);
            a2f = fmaf(wv.z, xw[kw + 3], a2f);
            a3f = fmaf(wv.w, xw[kw + 4], a3f);
        }
    }
    *(float4*)&out[(b * 256 + g * 16 + cc) * 3136 + (h0 + sh) * 56 + w0 + sw4] =
        make_float4(a0f, a1f, a2f, a3f);
}

extern "C" void kernel_launch(void* const* d_in, const int* in_sizes, int n_in,
                              void* d_out, int out_size, void* d_ws, size_t ws_size,
                              hipStream_t stream) {
    const float* x     = (const float*)d_in[0];
    const float* w1    = (const float*)d_in[1];
    const float* gamma = (const float*)d_in[2];
    const float* beta  = (const float*)d_in[3];
    const float* mean  = (const float*)d_in[4];
    const float* var   = (const float*)d_in[5];
    const float* cw    = (const float*)d_in[6];
    const float* cb    = (const float*)d_in[7];
    float* out = (float*)d_out;

    __fp16* mid = (__fp16*)d_ws;             // 1605632 B

    k1_conv1<<<dim3(98, 4), 256, 0, stream>>>(x, w1, gamma, beta, mean, var, mid);
    k23_fused<<<dim3(49, 16, 4), 256, 0, stream>>>(x, mid, cw, cb, out);
}